// Round 1
// baseline (165887.683 us; speedup 1.0000x reference)
//
#include <hip/hip_runtime.h>

#define NWG 32u

typedef __attribute__((ext_vector_type(4))) int   i32x4;
typedef __attribute__((ext_vector_type(8))) short s16x8;
typedef __attribute__((ext_vector_type(4))) float f32x4;

__device__ __forceinline__ unsigned short f2bf(float f) {
  unsigned u = __float_as_uint(f);
  unsigned r = u + 0x7FFFu + ((u >> 16) & 1u);
  return (unsigned short)(r >> 16);
}
__device__ __forceinline__ unsigned pack2bf(float lo, float hi) {
  return (unsigned)f2bf(lo) | ((unsigned)f2bf(hi) << 16);
}
__device__ __forceinline__ float bflo(unsigned u){ return __uint_as_float(u << 16); }
__device__ __forceinline__ float bfhi(unsigned u){ return __uint_as_float(u & 0xFFFF0000u); }

__device__ __forceinline__ float sigm(float x){ return 1.0f / (1.0f + __expf(-x)); }
__device__ __forceinline__ float tanh_(float x){
  float ax = fabsf(x);
  float e  = __expf(-2.0f * ax);
  float t  = (1.0f - e) / (1.0f + e);
  return copysignf(t, x);
}

// 32-WG device barrier: monotonically increasing counter, agent-scope.
__device__ __forceinline__ void gbar(unsigned* cnt, unsigned gen) {
  __syncthreads();   // compiler drains vmcnt before s_barrier -> prior stores complete
  if (threadIdx.x == 0) {
    __hip_atomic_fetch_add(cnt, 1u, __ATOMIC_RELEASE, __HIP_MEMORY_SCOPE_AGENT);
    const unsigned tgt = NWG * gen;
    while (__hip_atomic_load(cnt, __ATOMIC_ACQUIRE, __HIP_MEMORY_SCOPE_AGENT) < tgt)
      __builtin_amdgcn_s_sleep(1);
  }
  __syncthreads();
}

// ---------------- input projection: XP[b][j] = x @ in_proj_w.T + b ----------------
__global__ __launch_bounds__(256) void k_inproj(const float* __restrict__ x,
                                                const float* __restrict__ w,
                                                const float* __restrict__ bb,
                                                float* __restrict__ XP) {
  int idx = blockIdx.x * 256 + threadIdx.x;   // 0..16383 = b*512 + j
  int b = idx >> 9, j = idx & 511;
  float acc = bb[j];
#pragma unroll
  for (int k = 0; k < 12; ++k) acc += x[b * 12 + k] * w[j * 12 + k];
  XP[idx] = acc;
}

// ---------------- layer-0 input gates (constant over t): XG0[b][r] ----------------
__global__ __launch_bounds__(256) void k_xg0(const float* __restrict__ XP,
                                             const float* __restrict__ Wih,
                                             const float* __restrict__ bih,
                                             float* __restrict__ XG0) {
  int idx = blockIdx.x * 256 + threadIdx.x;   // 65536 threads
  int b = idx & 31;
  int r = idx >> 5;                           // 0..2047
  const float* wr = Wih + (size_t)r * 512;
  const float* xr = XP + b * 512;
  float acc = bih[r];
  for (int k = 0; k < 512; k += 4) {
    const f32x4 w4 = *(const f32x4*)(wr + k);
    const f32x4 x4 = *(const f32x4*)(xr + k);
    acc += w4[0]*x4[0] + w4[1]*x4[1] + w4[2]*x4[2] + w4[3]*x4[3];
  }
  XG0[b * 2048 + r] = acc;
}

// ---------------- recurrent scan for one layer ----------------
// grid 32 WGs x 256 thr. WG w owns h-cols [16w,16w+16). Wave v = gate v.
// Weights: bf16 MFMA B-fragments in registers. h: packed bf16 via agent atomics.
template<bool L0>
__global__ __launch_bounds__(256, 1) void k_scan(
    const float* __restrict__ Wih, const float* __restrict__ Whh,
    const float* __restrict__ bih, const float* __restrict__ bhh,
    int layer,
    const unsigned* __restrict__ HINu,   // l>=1: LN'd input, bf16 pairs [B][T][256]
    unsigned* __restrict__ RBu,          // raw out+res, bf16 pairs [B][T][256]
    const float* __restrict__ XG0,      // L0 only [B][2048]
    const float* __restrict__ XPp,      // L0 only [B][512]
    unsigned* __restrict__ Hst,          // [2][32][256] packed bf16
    unsigned* __restrict__ cnt)
{
  __shared__ char smem[65536];
  char* xarea = smem;            // 32 KB: staged LN'd input (l>=1) / L0 statics
  char* harea = smem + 32768;    // 32 KB: staged h
  float* gacc = (float*)(L0 ? (smem + 10240) : smem);   // [4][16][36] f32

  const int tid  = threadIdx.x;
  const int w    = blockIdx.x;
  const int lane = tid & 63;
  const int wv   = tid >> 6;     // wave = gate index
  const int j0   = w << 4;

  // ---- B-fragment preload (once per layer) ----
  s16x8 bfih[16], bfhh[16];
  {
    const int rcol = lane & 15;
    const int kg   = lane >> 4;
    const size_t rowbase = ((size_t)layer * 2048 + (size_t)(wv * 512 + j0 + rcol)) * 512;
    const float* ihr = Wih + rowbase;
    const float* hhr = Whh + rowbase;
#pragma unroll
    for (int kk = 0; kk < 16; ++kk) {
      const int k0 = kg * 8 + kk * 32;
      s16x8 v2;
#pragma unroll
      for (int j = 0; j < 8; ++j) v2[j] = (short)f2bf(hhr[k0 + j]);
      bfhh[kk] = v2;
      if (!L0) {
        s16x8 v1;
#pragma unroll
        for (int j = 0; j < 8; ++j) v1[j] = (short)f2bf(ihr[k0 + j]);
        bfih[kk] = v1;
      }
    }
  }

  const int ub = tid >> 3;            // batch row this thread updates
  const int jp = tid & 7;             // col-pair within WG
  const int kpglob = (j0 >> 1) + jp;  // global u32 pair index

  float bs[4][2];
#pragma unroll
  for (int g = 0; g < 4; ++g)
#pragma unroll
    for (int c = 0; c < 2; ++c) {
      const size_t r = (size_t)layer * 2048 + g * 512 + j0 + 2 * jp + c;
      float vv = bhh[r];
      if (!L0) vv += bih[r];          // L0: b_ih folded into XG0
      bs[g][c] = vv;
    }

  if (L0) {
    float* xg0s = (float*)smem;           // [4][32][16]
    float* xps  = (float*)(smem + 8192);  // [32][16]
    for (int i = tid; i < 2048; i += 256) {
      int g = i >> 9, b = (i >> 4) & 31, jl = i & 15;
      xg0s[i] = XG0[b * 2048 + g * 512 + j0 + jl];
    }
    for (int i = tid; i < 512; i += 256) {
      int b = i >> 4, jl = i & 15;
      xps[i] = XPp[b * 512 + j0 + jl];
    }
  }

  // zero own slice of h buffer 0 (h0 = 0)
  __hip_atomic_store(&Hst[(ub << 8) + kpglob], 0u, __ATOMIC_RELAXED, __HIP_MEMORY_SCOPE_AGENT);

  unsigned gen = 1;
  gbar(cnt, gen);

  float xin0_c = 0.f, xin1_c = 0.f;
  if (L0) {
    const float* xps = (const float*)(smem + 8192);
    xin0_c = xps[ub * 16 + 2 * jp];
    xin1_c = xps[ub * 16 + 2 * jp + 1];
  }

  const int rA  = lane & 15;
  const int kg2 = lane >> 4;
  const int swz = (rA & 7) << 4;
  const int ab0 = rA * 1024 + kg2 * 16;
  const int ab1 = ab0 + 16384;

  float creg0 = 0.f, creg1 = 0.f;

#pragma unroll 1
  for (int t = 0; t < 2048; ++t) {
    // ---- stage LN'd input x[:,t,:] into xarea (swizzled) ----
    if (!L0) {
#pragma unroll
      for (int q = 0; q < 32; ++q) {
        unsigned v = HINu[((size_t)q * 2048 + t) * 256 + tid];
        *(unsigned*)(xarea + ((q * 1024 + tid * 4) ^ ((q & 7) << 4))) = v;
      }
    }
    // ---- stage h[t-1] from device-coherent buffer ----
    {
      const unsigned long long* hs = (const unsigned long long*)(Hst + ((t & 1) << 13));
#pragma unroll
      for (int it = 0; it < 16; ++it) {
        const int flat = it * 256 + tid;
        unsigned long long v = __hip_atomic_load(hs + flat, __ATOMIC_RELAXED, __HIP_MEMORY_SCOPE_AGENT);
        const int q = flat >> 7, kp2 = flat & 127;
        *(unsigned long long*)(harea + ((q * 1024 + kp2 * 8) ^ ((q & 7) << 4))) = v;
      }
    }
    __syncthreads();

    float xin0, xin1;
    if (!L0) {
      const unsigned xu = *(const unsigned*)(xarea + (((ub * 1024) + kpglob * 4) ^ ((ub & 7) << 4)));
      xin0 = bflo(xu); xin1 = bfhi(xu);
    } else { xin0 = xin0_c; xin1 = xin1_c; }

    // ---- gate GEMM: acc[b-tile][16 gate cols] over K (ih: 512, hh: 512) ----
    f32x4 acc0 = {0.f,0.f,0.f,0.f};
    f32x4 acc1 = {0.f,0.f,0.f,0.f};
    if (!L0) {
#pragma unroll
      for (int kk = 0; kk < 16; ++kk) {
        const i32x4 a0 = *(const i32x4*)(xarea + ((ab0 + kk * 64) ^ swz));
        const i32x4 a1 = *(const i32x4*)(xarea + ((ab1 + kk * 64) ^ swz));
        acc0 = __builtin_amdgcn_mfma_f32_16x16x32_bf16(__builtin_bit_cast(s16x8, a0), bfih[kk], acc0, 0, 0, 0);
        acc1 = __builtin_amdgcn_mfma_f32_16x16x32_bf16(__builtin_bit_cast(s16x8, a1), bfih[kk], acc1, 0, 0, 0);
      }
    }
#pragma unroll
    for (int kk = 0; kk < 16; ++kk) {
      const i32x4 a0 = *(const i32x4*)(harea + ((ab0 + kk * 64) ^ swz));
      const i32x4 a1 = *(const i32x4*)(harea + ((ab1 + kk * 64) ^ swz));
      acc0 = __builtin_amdgcn_mfma_f32_16x16x32_bf16(__builtin_bit_cast(s16x8, a0), bfhh[kk], acc0, 0, 0, 0);
      acc1 = __builtin_amdgcn_mfma_f32_16x16x32_bf16(__builtin_bit_cast(s16x8, a1), bfhh[kk], acc1, 0, 0, 0);
    }
    __syncthreads();   // all LDS reads done before gacc aliases xarea
    {
      float* gp = gacc + (wv * 16 + rA) * 36 + kg2 * 4;  // [gate][col][row]
      *(f32x4*)gp        = acc0;          // rows kg2*4..+3   (b 0..15)
      *(f32x4*)(gp + 16) = acc1;          // rows 16+kg2*4..  (b 16..31)
    }
    __syncthreads();

    // ---- per-(b, col-pair) LSTM cell update ----
    float pre[4][2];
#pragma unroll
    for (int g = 0; g < 4; ++g)
#pragma unroll
      for (int c = 0; c < 2; ++c) {
        float vv = gacc[(g * 16 + 2 * jp + c) * 36 + ub] + bs[g][c];
        if (L0) vv += ((const float*)smem)[(g * 32 + ub) * 16 + 2 * jp + c];
        pre[g][c] = vv;
      }

    float i0 = sigm(pre[0][0]), ff0 = sigm(pre[1][0]), g0 = tanh_(pre[2][0]), o0 = sigm(pre[3][0]);
    creg0 = ff0 * creg0 + i0 * g0;
    float h0 = o0 * tanh_(creg0);
    float i1 = sigm(pre[0][1]), ff1 = sigm(pre[1][1]), g1 = tanh_(pre[2][1]), o1 = sigm(pre[3][1]);
    creg1 = ff1 * creg1 + i1 * g1;
    float h1 = o1 * tanh_(creg1);

    RBu[((size_t)ub * 2048 + t) * 256 + kpglob] = pack2bf(h0 + xin0, h1 + xin1);
    __hip_atomic_store(&Hst[(((t + 1) & 1) << 13) + (ub << 8) + kpglob], pack2bf(h0, h1),
                       __ATOMIC_RELAXED, __HIP_MEMORY_SCOPE_AGENT);
    ++gen;
    gbar(cnt, gen);
  }
}

// ---------------- fused LayerNorm: RA = LN(RB) with params of `layer` ----------------
__global__ __launch_bounds__(256) void k_ln(const unsigned* __restrict__ Rin,
                                            unsigned* __restrict__ Rout,
                                            const float* __restrict__ lnS,
                                            const float* __restrict__ lnB, int layer) {
  int row  = blockIdx.x * 4 + (threadIdx.x >> 6);   // b*T + t
  int lane = threadIdx.x & 63;
  const i32x4 v = *(const i32x4*)(Rin + (size_t)row * 256 + lane * 4);
  float xv[8];
#pragma unroll
  for (int j = 0; j < 4; ++j) {
    unsigned u = (unsigned)v[j];
    xv[2*j]   = bflo(u);
    xv[2*j+1] = bfhi(u);
  }
  float s = 0.f, s2 = 0.f;
#pragma unroll
  for (int j = 0; j < 8; ++j) { s += xv[j]; s2 += xv[j] * xv[j]; }
#pragma unroll
  for (int m = 1; m < 64; m <<= 1) { s += __shfl_xor(s, m, 64); s2 += __shfl_xor(s2, m, 64); }
  float mu  = s * (1.f / 512.f);
  float var = s2 * (1.f / 512.f) - mu * mu;
  float rs  = rsqrtf(var + 1e-5f);
  const float* Sp = lnS + layer * 512 + lane * 8;
  const float* Bp = lnB + layer * 512 + lane * 8;
  i32x4 ov;
#pragma unroll
  for (int j = 0; j < 4; ++j) {
    float a = (xv[2*j]   - mu) * rs * Sp[2*j]   + Bp[2*j];
    float b = (xv[2*j+1] - mu) * rs * Sp[2*j+1] + Bp[2*j+1];
    ov[j] = (int)pack2bf(a, b);
  }
  *(i32x4*)(Rout + (size_t)row * 256 + lane * 4) = ov;
}

// ---------------- output head: y[b,t] = HIN . out_w + out_b ----------------
__global__ __launch_bounds__(256) void k_out(const unsigned* __restrict__ Rin,
                                             const float* __restrict__ ow,
                                             const float* __restrict__ ob,
                                             float* __restrict__ y) {
  int row  = blockIdx.x * 4 + (threadIdx.x >> 6);
  int lane = threadIdx.x & 63;
  const i32x4 v = *(const i32x4*)(Rin + (size_t)row * 256 + lane * 4);
  const float* wp = ow + lane * 8;
  float s = 0.f;
#pragma unroll
  for (int j = 0; j < 4; ++j) {
    unsigned u = (unsigned)v[j];
    s += bflo(u) * wp[2*j] + bfhi(u) * wp[2*j+1];
  }
#pragma unroll
  for (int m = 1; m < 64; m <<= 1) s += __shfl_xor(s, m, 64);
  if (lane == 0) y[row] = s + ob[0];
}

extern "C" void kernel_launch(void* const* d_in, const int* in_sizes, int n_in,
                              void* d_out, int out_size, void* d_ws, size_t ws_size,
                              hipStream_t stream) {
  (void)in_sizes; (void)n_in; (void)out_size; (void)ws_size;
  const float* x   = (const float*)d_in[0];
  const float* ipw = (const float*)d_in[1];
  const float* ipb = (const float*)d_in[2];
  const float* Wih = (const float*)d_in[3];
  const float* Whh = (const float*)d_in[4];
  const float* bih = (const float*)d_in[5];
  const float* bhh = (const float*)d_in[6];
  const float* lnS = (const float*)d_in[7];
  const float* lnB = (const float*)d_in[8];
  const float* ow  = (const float*)d_in[9];
  const float* ob  = (const float*)d_in[10];
  float* y = (float*)d_out;

  char* ws = (char*)d_ws;
  unsigned* cnt = (unsigned*)ws;                              // 16 u32 counters
  float* XP     = (float*)(ws + 256);                         // 64 KB
  float* XG0    = (float*)(ws + 256 + 65536);                 // 256 KB
  unsigned* Hst = (unsigned*)(ws + 256 + 65536 + 262144);     // 64 KB
  unsigned* RA  = (unsigned*)(ws + 1048576);                  // 67.1 MB (LN'd input)
  unsigned* RB  = (unsigned*)(ws + 1048576 + 67108864);       // 67.1 MB (raw out+res)

  hipMemsetAsync(cnt, 0, 64, stream);
  k_inproj<<<64, 256, 0, stream>>>(x, ipw, ipb, XP);
  k_xg0<<<256, 256, 0, stream>>>(XP, Wih, bih, XG0);

  k_scan<true><<<32, 256, 0, stream>>>(Wih, Whh, bih, bhh, 0, nullptr, RB, XG0, XP, Hst, cnt + 0);
  k_ln<<<16384, 256, 0, stream>>>(RB, RA, lnS, lnB, 0);
  for (int l = 1; l < 6; ++l) {
    k_scan<false><<<32, 256, 0, stream>>>(Wih, Whh, bih, bhh, l, RA, RB, nullptr, nullptr, Hst, cnt + l);
    k_ln<<<16384, 256, 0, stream>>>(RB, RA, lnS, lnB, l);
  }
  k_out<<<16384, 256, 0, stream>>>(RA, ow, ob, y);
}

// Round 2
// 85537.415 us; speedup vs baseline: 1.9394x; 1.9394x over previous
//
#include <hip/hip_runtime.h>

#define NWG 32u

typedef __attribute__((ext_vector_type(4))) int   i32x4;
typedef __attribute__((ext_vector_type(8))) short s16x8;
typedef __attribute__((ext_vector_type(4))) float f32x4;

__device__ __forceinline__ unsigned short f2bf(float f) {
  unsigned u = __float_as_uint(f);
  unsigned r = u + 0x7FFFu + ((u >> 16) & 1u);
  return (unsigned short)(r >> 16);
}
__device__ __forceinline__ unsigned pack2bf(float lo, float hi) {
  return (unsigned)f2bf(lo) | ((unsigned)f2bf(hi) << 16);
}
__device__ __forceinline__ float bflo(unsigned u){ return __uint_as_float(u << 16); }
__device__ __forceinline__ float bfhi(unsigned u){ return __uint_as_float(u & 0xFFFF0000u); }

__device__ __forceinline__ float sigm(float x){ return 1.0f / (1.0f + __expf(-x)); }
__device__ __forceinline__ float tanh_(float x){
  float ax = fabsf(x);
  float e  = __expf(-2.0f * ax);
  float t  = (1.0f - e) / (1.0f + e);
  return copysignf(t, x);
}

// ---------------- input projection: XP[b][j] = x @ in_proj_w.T + b ----------------
__global__ __launch_bounds__(256) void k_inproj(const float* __restrict__ x,
                                                const float* __restrict__ w,
                                                const float* __restrict__ bb,
                                                float* __restrict__ XP) {
  int idx = blockIdx.x * 256 + threadIdx.x;   // 0..16383 = b*512 + j
  int b = idx >> 9, j = idx & 511;
  float acc = bb[j];
#pragma unroll
  for (int k = 0; k < 12; ++k) acc += x[b * 12 + k] * w[j * 12 + k];
  XP[idx] = acc;
}

// ---------------- layer-0 input gates (constant over t): XG0[b][r] ----------------
__global__ __launch_bounds__(256) void k_xg0(const float* __restrict__ XP,
                                             const float* __restrict__ Wih,
                                             const float* __restrict__ bih,
                                             float* __restrict__ XG0) {
  int idx = blockIdx.x * 256 + threadIdx.x;   // 65536 threads
  int b = idx & 31;
  int r = idx >> 5;                           // 0..2047
  const float* wr = Wih + (size_t)r * 512;
  const float* xr = XP + b * 512;
  float acc = bih[r];
  for (int k = 0; k < 512; k += 4) {
    const f32x4 w4 = *(const f32x4*)(wr + k);
    const f32x4 x4 = *(const f32x4*)(xr + k);
    acc += w4[0]*x4[0] + w4[1]*x4[1] + w4[2]*x4[2] + w4[3]*x4[3];
  }
  XG0[b * 2048 + r] = acc;
}

// ---------------- recurrent scan for one layer ----------------
// grid 32 WGs x 256 thr. WG w owns h-cols [16w,16w+16). Wave v = gate v.
// Weights: bf16 MFMA B-fragments in registers. h: packed bf16 via sc1 atomics (LLC-coherent).
// Barrier: per-WG release flag + relaxed polling (no RMW, no acquire-invalidate storms).
template<bool L0>
__global__ __launch_bounds__(256, 1) void k_scan(
    const float* __restrict__ Wih, const float* __restrict__ Whh,
    const float* __restrict__ bih, const float* __restrict__ bhh,
    int layer,
    const unsigned* __restrict__ HINu,   // l>=1: LN'd input, bf16 pairs [B][T][256]
    unsigned* __restrict__ RBu,          // raw out+res, bf16 pairs [B][T][256]
    const float* __restrict__ XG0,      // L0 only [B][2048]
    const float* __restrict__ XPp,      // L0 only [B][512]
    unsigned* __restrict__ Hst,          // [2][32][256] packed bf16
    unsigned* __restrict__ flg)          // [32] per-WG arrival flags (this layer)
{
  __shared__ char smem[65536];
  char* xarea = smem;            // 32 KB: staged LN'd input (l>=1) / L0 statics
  char* harea = smem + 32768;    // 32 KB: staged h
  float* gacc = (float*)(L0 ? (smem + 10240) : smem);   // [4][16][36] f32

  const int tid  = threadIdx.x;
  const int w    = blockIdx.x;
  const int lane = tid & 63;
  const int wv   = tid >> 6;     // wave = gate index
  const int j0   = w << 4;

  // ---- B-fragment preload (once per layer) ----
  s16x8 bfih[16], bfhh[16];
  {
    const int rcol = lane & 15;
    const int kg   = lane >> 4;
    const size_t rowbase = ((size_t)layer * 2048 + (size_t)(wv * 512 + j0 + rcol)) * 512;
    const float* ihr = Wih + rowbase;
    const float* hhr = Whh + rowbase;
#pragma unroll
    for (int kk = 0; kk < 16; ++kk) {
      const int k0 = kg * 8 + kk * 32;
      s16x8 v2;
#pragma unroll
      for (int j = 0; j < 8; ++j) v2[j] = (short)f2bf(hhr[k0 + j]);
      bfhh[kk] = v2;
      if (!L0) {
        s16x8 v1;
#pragma unroll
        for (int j = 0; j < 8; ++j) v1[j] = (short)f2bf(ihr[k0 + j]);
        bfih[kk] = v1;
      }
    }
  }

  const int ub = tid >> 3;            // batch row this thread updates
  const int jp = tid & 7;             // col-pair within WG
  const int kpglob = (j0 >> 1) + jp;  // global u32 pair index

  float bs[4][2];
#pragma unroll
  for (int g = 0; g < 4; ++g)
#pragma unroll
    for (int c = 0; c < 2; ++c) {
      const size_t r = (size_t)layer * 2048 + g * 512 + j0 + 2 * jp + c;
      float vv = bhh[r];
      if (!L0) vv += bih[r];          // L0: b_ih folded into XG0
      bs[g][c] = vv;
    }

  if (L0) {
    float* xg0s = (float*)smem;           // [4][32][16]
    float* xps  = (float*)(smem + 8192);  // [32][16]
    for (int i = tid; i < 2048; i += 256) {
      int g = i >> 9, b = (i >> 4) & 31, jl = i & 15;
      xg0s[i] = XG0[b * 2048 + g * 512 + j0 + jl];
    }
    for (int i = tid; i < 512; i += 256) {
      int b = i >> 4, jl = i & 15;
      xps[i] = XPp[b * 512 + j0 + jl];
    }
  }

  // zero own slice of h buffer 0 (h0 = 0)
  __hip_atomic_store(&Hst[(ub << 8) + kpglob], 0u, __ATOMIC_RELAXED, __HIP_MEMORY_SCOPE_AGENT);

  // ---- barrier gen 1, overlapped with x[0] staging ----
  __syncthreads();
  if (tid == 0)
    __hip_atomic_store(flg + w, 1u, __ATOMIC_RELEASE, __HIP_MEMORY_SCOPE_AGENT);
  if (!L0) {
#pragma unroll
    for (int q = 0; q < 32; ++q) {
      unsigned v = HINu[((size_t)q * 2048 + 0) * 256 + tid];
      *(unsigned*)(xarea + ((q * 1024 + tid * 4) ^ ((q & 7) << 4))) = v;
    }
  }
  if (tid < 64) {
    for (;;) {
      unsigned v = __hip_atomic_load(flg + (lane & 31), __ATOMIC_RELAXED, __HIP_MEMORY_SCOPE_AGENT);
      if (__all((int)(v >= 1u))) break;
      __builtin_amdgcn_s_sleep(2);
    }
  }
  __syncthreads();

  float xin0_c = 0.f, xin1_c = 0.f;
  if (L0) {
    const float* xps = (const float*)(smem + 8192);
    xin0_c = xps[ub * 16 + 2 * jp];
    xin1_c = xps[ub * 16 + 2 * jp + 1];
  }

  const int rA  = lane & 15;
  const int kg2 = lane >> 4;
  const int swz = (rA & 7) << 4;
  const int ab0 = rA * 1024 + kg2 * 16;
  const int ab1 = ab0 + 16384;

  float creg0 = 0.f, creg1 = 0.f;

#pragma unroll 1
  for (int t = 0; t < 2048; ++t) {
    // ---- stage h[t-1] from LLC-coherent buffer ----
    {
      const unsigned long long* hs = (const unsigned long long*)(Hst + ((t & 1) << 13));
#pragma unroll
      for (int it = 0; it < 16; ++it) {
        const int flat = it * 256 + tid;
        unsigned long long v = __hip_atomic_load(hs + flat, __ATOMIC_RELAXED, __HIP_MEMORY_SCOPE_AGENT);
        const int q = flat >> 7, kp2 = flat & 127;
        *(unsigned long long*)(harea + ((q * 1024 + kp2 * 8) ^ ((q & 7) << 4))) = v;
      }
    }
    __syncthreads();

    float xin0, xin1;
    if (!L0) {
      const unsigned xu = *(const unsigned*)(xarea + (((ub * 1024) + kpglob * 4) ^ ((ub & 7) << 4)));
      xin0 = bflo(xu); xin1 = bfhi(xu);
    } else { xin0 = xin0_c; xin1 = xin1_c; }

    // ---- gate GEMM: 4 independent MFMA chains for ILP ----
    f32x4 acc0, acc1;
    if (!L0) {
      f32x4 ai0 = {0.f,0.f,0.f,0.f}, ai1 = {0.f,0.f,0.f,0.f};
      f32x4 ah0 = {0.f,0.f,0.f,0.f}, ah1 = {0.f,0.f,0.f,0.f};
#pragma unroll
      for (int kk = 0; kk < 16; ++kk) {
        const i32x4 x0 = *(const i32x4*)(xarea + ((ab0 + kk * 64) ^ swz));
        const i32x4 x1 = *(const i32x4*)(xarea + ((ab1 + kk * 64) ^ swz));
        const i32x4 h0 = *(const i32x4*)(harea + ((ab0 + kk * 64) ^ swz));
        const i32x4 h1 = *(const i32x4*)(harea + ((ab1 + kk * 64) ^ swz));
        ai0 = __builtin_amdgcn_mfma_f32_16x16x32_bf16(__builtin_bit_cast(s16x8, x0), bfih[kk], ai0, 0, 0, 0);
        ai1 = __builtin_amdgcn_mfma_f32_16x16x32_bf16(__builtin_bit_cast(s16x8, x1), bfih[kk], ai1, 0, 0, 0);
        ah0 = __builtin_amdgcn_mfma_f32_16x16x32_bf16(__builtin_bit_cast(s16x8, h0), bfhh[kk], ah0, 0, 0, 0);
        ah1 = __builtin_amdgcn_mfma_f32_16x16x32_bf16(__builtin_bit_cast(s16x8, h1), bfhh[kk], ah1, 0, 0, 0);
      }
      acc0 = ai0 + ah0; acc1 = ai1 + ah1;
    } else {
      f32x4 a0a = {0.f,0.f,0.f,0.f}, a1a = {0.f,0.f,0.f,0.f};
      f32x4 a0b = {0.f,0.f,0.f,0.f}, a1b = {0.f,0.f,0.f,0.f};
#pragma unroll
      for (int kk = 0; kk < 8; ++kk) {
        const i32x4 h0a = *(const i32x4*)(harea + ((ab0 + kk * 64) ^ swz));
        const i32x4 h1a = *(const i32x4*)(harea + ((ab1 + kk * 64) ^ swz));
        const i32x4 h0b = *(const i32x4*)(harea + ((ab0 + (kk + 8) * 64) ^ swz));
        const i32x4 h1b = *(const i32x4*)(harea + ((ab1 + (kk + 8) * 64) ^ swz));
        a0a = __builtin_amdgcn_mfma_f32_16x16x32_bf16(__builtin_bit_cast(s16x8, h0a), bfhh[kk], a0a, 0, 0, 0);
        a1a = __builtin_amdgcn_mfma_f32_16x16x32_bf16(__builtin_bit_cast(s16x8, h1a), bfhh[kk], a1a, 0, 0, 0);
        a0b = __builtin_amdgcn_mfma_f32_16x16x32_bf16(__builtin_bit_cast(s16x8, h0b), bfhh[kk + 8], a0b, 0, 0, 0);
        a1b = __builtin_amdgcn_mfma_f32_16x16x32_bf16(__builtin_bit_cast(s16x8, h1b), bfhh[kk + 8], a1b, 0, 0, 0);
      }
      acc0 = a0a + a0b; acc1 = a1a + a1b;
    }
    __syncthreads();   // all LDS reads done before gacc aliases xarea
    {
      float* gp = gacc + (wv * 16 + rA) * 36 + kg2 * 4;  // [gate][col][row]
      *(f32x4*)gp        = acc0;          // rows kg2*4..+3   (b 0..15)
      *(f32x4*)(gp + 16) = acc1;          // rows 16+kg2*4..  (b 16..31)
    }
    __syncthreads();

    // ---- per-(b, col-pair) LSTM cell update ----
    float pre[4][2];
#pragma unroll
    for (int g = 0; g < 4; ++g)
#pragma unroll
      for (int c = 0; c < 2; ++c) {
        float vv = gacc[(g * 16 + 2 * jp + c) * 36 + ub] + bs[g][c];
        if (L0) vv += ((const float*)smem)[(g * 32 + ub) * 16 + 2 * jp + c];
        pre[g][c] = vv;
      }

    float i0 = sigm(pre[0][0]), ff0 = sigm(pre[1][0]), g0 = tanh_(pre[2][0]), o0 = sigm(pre[3][0]);
    creg0 = ff0 * creg0 + i0 * g0;
    float h0 = o0 * tanh_(creg0);
    float i1 = sigm(pre[0][1]), ff1 = sigm(pre[1][1]), g1 = tanh_(pre[2][1]), o1 = sigm(pre[3][1]);
    creg1 = ff1 * creg1 + i1 * g1;
    float h1 = o1 * tanh_(creg1);

    __hip_atomic_store(&RBu[((size_t)ub * 2048 + t) * 256 + kpglob], pack2bf(h0 + xin0, h1 + xin1),
                       __ATOMIC_RELAXED, __HIP_MEMORY_SCOPE_AGENT);
    __hip_atomic_store(&Hst[(((t + 1) & 1) << 13) + (ub << 8) + kpglob], pack2bf(h0, h1),
                       __ATOMIC_RELAXED, __HIP_MEMORY_SCOPE_AGENT);

    if (t == 2047) break;   // no consumer of h[2048]; kernel-end handles RBu visibility

    // ---- barrier gen t+2, overlapped with x[t+1] staging ----
    __syncthreads();        // gacc reads done; per-wave vmcnt drained before barrier
    if (tid == 0)
      __hip_atomic_store(flg + w, (unsigned)(t + 2), __ATOMIC_RELEASE, __HIP_MEMORY_SCOPE_AGENT);
    if (!L0) {
#pragma unroll
      for (int q = 0; q < 32; ++q) {
        unsigned v = HINu[((size_t)q * 2048 + (t + 1)) * 256 + tid];
        *(unsigned*)(xarea + ((q * 1024 + tid * 4) ^ ((q & 7) << 4))) = v;
      }
    }
    if (tid < 64) {
      const unsigned need = (unsigned)(t + 2);
      for (;;) {
        unsigned v = __hip_atomic_load(flg + (lane & 31), __ATOMIC_RELAXED, __HIP_MEMORY_SCOPE_AGENT);
        if (__all((int)(v >= need))) break;
        __builtin_amdgcn_s_sleep(2);
      }
    }
    __syncthreads();
  }
}

// ---------------- fused LayerNorm: RA = LN(RB) with params of `layer` ----------------
__global__ __launch_bounds__(256) void k_ln(const unsigned* __restrict__ Rin,
                                            unsigned* __restrict__ Rout,
                                            const float* __restrict__ lnS,
                                            const float* __restrict__ lnB, int layer) {
  int row  = blockIdx.x * 4 + (threadIdx.x >> 6);   // b*T + t
  int lane = threadIdx.x & 63;
  const i32x4 v = *(const i32x4*)(Rin + (size_t)row * 256 + lane * 4);
  float xv[8];
#pragma unroll
  for (int j = 0; j < 4; ++j) {
    unsigned u = (unsigned)v[j];
    xv[2*j]   = bflo(u);
    xv[2*j+1] = bfhi(u);
  }
  float s = 0.f, s2 = 0.f;
#pragma unroll
  for (int j = 0; j < 8; ++j) { s += xv[j]; s2 += xv[j] * xv[j]; }
#pragma unroll
  for (int m = 1; m < 64; m <<= 1) { s += __shfl_xor(s, m, 64); s2 += __shfl_xor(s2, m, 64); }
  float mu  = s * (1.f / 512.f);
  float var = s2 * (1.f / 512.f) - mu * mu;
  float rs  = rsqrtf(var + 1e-5f);
  const float* Sp = lnS + layer * 512 + lane * 8;
  const float* Bp = lnB + layer * 512 + lane * 8;
  i32x4 ov;
#pragma unroll
  for (int j = 0; j < 4; ++j) {
    float a = (xv[2*j]   - mu) * rs * Sp[2*j]   + Bp[2*j];
    float b = (xv[2*j+1] - mu) * rs * Sp[2*j+1] + Bp[2*j+1];
    ov[j] = (int)pack2bf(a, b);
  }
  *(i32x4*)(Rout + (size_t)row * 256 + lane * 4) = ov;
}

// ---------------- output head: y[b,t] = HIN . out_w + out_b ----------------
__global__ __launch_bounds__(256) void k_out(const unsigned* __restrict__ Rin,
                                             const float* __restrict__ ow,
                                             const float* __restrict__ ob,
                                             float* __restrict__ y) {
  int row  = blockIdx.x * 4 + (threadIdx.x >> 6);
  int lane = threadIdx.x & 63;
  const i32x4 v = *(const i32x4*)(Rin + (size_t)row * 256 + lane * 4);
  const float* wp = ow + lane * 8;
  float s = 0.f;
#pragma unroll
  for (int j = 0; j < 4; ++j) {
    unsigned u = (unsigned)v[j];
    s += bflo(u) * wp[2*j] + bfhi(u) * wp[2*j+1];
  }
#pragma unroll
  for (int m = 1; m < 64; m <<= 1) s += __shfl_xor(s, m, 64);
  if (lane == 0) y[row] = s + ob[0];
}

extern "C" void kernel_launch(void* const* d_in, const int* in_sizes, int n_in,
                              void* d_out, int out_size, void* d_ws, size_t ws_size,
                              hipStream_t stream) {
  (void)in_sizes; (void)n_in; (void)out_size; (void)ws_size;
  const float* x   = (const float*)d_in[0];
  const float* ipw = (const float*)d_in[1];
  const float* ipb = (const float*)d_in[2];
  const float* Wih = (const float*)d_in[3];
  const float* Whh = (const float*)d_in[4];
  const float* bih = (const float*)d_in[5];
  const float* bhh = (const float*)d_in[6];
  const float* lnS = (const float*)d_in[7];
  const float* lnB = (const float*)d_in[8];
  const float* ow  = (const float*)d_in[9];
  const float* ob  = (const float*)d_in[10];
  float* y = (float*)d_out;

  char* ws = (char*)d_ws;
  unsigned* flg = (unsigned*)ws;                              // [6][32] flags
  float* XP     = (float*)(ws + 4096);                        // 64 KB
  float* XG0    = (float*)(ws + 4096 + 65536);                // 256 KB
  unsigned* Hst = (unsigned*)(ws + 4096 + 65536 + 262144);    // 64 KB
  unsigned* RA  = (unsigned*)(ws + 1048576);                  // 67.1 MB (LN'd input)
  unsigned* RB  = (unsigned*)(ws + 1048576 + 67108864);       // 67.1 MB (raw out+res)

  hipMemsetAsync(flg, 0, 6 * 32 * 4, stream);
  k_inproj<<<64, 256, 0, stream>>>(x, ipw, ipb, XP);
  k_xg0<<<256, 256, 0, stream>>>(XP, Wih, bih, XG0);

  k_scan<true><<<32, 256, 0, stream>>>(Wih, Whh, bih, bhh, 0, nullptr, RB, XG0, XP, Hst, flg + 0);
  k_ln<<<16384, 256, 0, stream>>>(RB, RA, lnS, lnB, 0);
  for (int l = 1; l < 6; ++l) {
    k_scan<false><<<32, 256, 0, stream>>>(Wih, Whh, bih, bhh, l, RA, RB, nullptr, nullptr, Hst, flg + l * 32);
    k_ln<<<16384, 256, 0, stream>>>(RB, RA, lnS, lnB, l);
  }
  k_out<<<16384, 256, 0, stream>>>(RA, ow, ob, y);
}

// Round 3
// 19280.745 us; speedup vs baseline: 8.6038x; 4.4364x over previous
//
#include <hip/hip_runtime.h>

#define NS 2058   // supersteps: 2048 + 2*5 skew

typedef __attribute__((ext_vector_type(4))) int   i32x4;
typedef __attribute__((ext_vector_type(8))) short s16x8;
typedef __attribute__((ext_vector_type(4))) float f32x4;

__device__ __forceinline__ unsigned short f2bf(float f) {
  unsigned u = __float_as_uint(f);
  unsigned r = u + 0x7FFFu + ((u >> 16) & 1u);
  return (unsigned short)(r >> 16);
}
__device__ __forceinline__ unsigned pack2bf(float lo, float hi) {
  return (unsigned)f2bf(lo) | ((unsigned)f2bf(hi) << 16);
}
__device__ __forceinline__ float bflo(unsigned u){ return __uint_as_float(u << 16); }
__device__ __forceinline__ float bfhi(unsigned u){ return __uint_as_float(u & 0xFFFF0000u); }

__device__ __forceinline__ float sigm(float x){ return 1.0f / (1.0f + __expf(-x)); }
__device__ __forceinline__ float tanh_(float x){
  float ax = fabsf(x);
  float e  = __expf(-2.0f * ax);
  float t  = (1.0f - e) / (1.0f + e);
  return copysignf(t, x);
}

// ---------------- input projection ----------------
__global__ __launch_bounds__(256) void k_inproj(const float* __restrict__ x,
                                                const float* __restrict__ w,
                                                const float* __restrict__ bb,
                                                float* __restrict__ XP) {
  int idx = blockIdx.x * 256 + threadIdx.x;
  int b = idx >> 9, j = idx & 511;
  float acc = bb[j];
#pragma unroll
  for (int k = 0; k < 12; ++k) acc += x[b * 12 + k] * w[j * 12 + k];
  XP[idx] = acc;
}

// ---------------- layer-0 input gates (constant over t) ----------------
__global__ __launch_bounds__(256) void k_xg0(const float* __restrict__ XP,
                                             const float* __restrict__ Wih,
                                             const float* __restrict__ bih,
                                             float* __restrict__ XG0) {
  int idx = blockIdx.x * 256 + threadIdx.x;
  int b = idx & 31;
  int r = idx >> 5;
  const float* wr = Wih + (size_t)r * 512;
  const float* xr = XP + b * 512;
  float acc = bih[r];
  for (int k = 0; k < 512; k += 4) {
    const f32x4 w4 = *(const f32x4*)(wr + k);
    const f32x4 x4 = *(const f32x4*)(xr + k);
    acc += w4[0]*x4[0] + w4[1]*x4[1] + w4[2]*x4[2] + w4[3]*x4[3];
  }
  XG0[b * 2048 + r] = acc;
}

// ---------------- 6-layer pipelined scan (192 WGs, skew=2) ----------------
// WG wgid: layer = wgid>>5, w = wgid&31 owns h-cols [16w,16w+16). Wave = gate.
// Superstep s: layer computes t = s - 2*layer; consumer-side LN of layer-1's
// row t+1 is prefetched/staged during s (off critical path, behind flag store).
__global__ __launch_bounds__(256, 1) void k_pipe(
    const float* __restrict__ Wih, const float* __restrict__ Whh,
    const float* __restrict__ bih, const float* __restrict__ bhh,
    const float* __restrict__ lnS, const float* __restrict__ lnB,
    const float* __restrict__ XG0, const float* __restrict__ XP,
    unsigned* __restrict__ Hst,              // [6][2][32][256] packed bf16
    unsigned* __restrict__ Roll,             // [5][4][32][256] raw out+res rows
    unsigned long long* __restrict__ Part,   // [5][4][32 wg][32 b] {sum,sumsq}
    unsigned* __restrict__ RB,               // [32][2048][256] layer-5 raw rows
    unsigned* __restrict__ flg)              // [192]
{
  __shared__ char smem[65536];
  char* xarea = smem;            // 32 KB: LN'd input row (l>=1) / L0 statics
  char* harea = smem + 32768;    // 32 KB: staged h (aliased as LN scratch in phase D)

  const int tid   = threadIdx.x;
  const int wgid  = blockIdx.x;
  const int layer = wgid >> 5;
  const int w     = wgid & 31;
  const int lane  = tid & 63;
  const int wv    = tid >> 6;    // wave = gate index
  const int j0    = w << 4;
  float* gacc = (float*)(layer == 0 ? (smem + 10240) : smem);   // [4][16][36] f32

  unsigned* HstL = Hst + layer * 16384;

  // ---- B-fragment preload ----
  s16x8 bfih[16], bfhh[16];
  {
    const int rcol = lane & 15;
    const int kg   = lane >> 4;
    const size_t rowbase = ((size_t)layer * 2048 + (size_t)(wv * 512 + j0 + rcol)) * 512;
    const float* ihr = Wih + rowbase;
    const float* hhr = Whh + rowbase;
#pragma unroll
    for (int kk = 0; kk < 16; ++kk) {
      const int k0 = kg * 8 + kk * 32;
      s16x8 v2;
#pragma unroll
      for (int j = 0; j < 8; ++j) v2[j] = (short)f2bf(hhr[k0 + j]);
      bfhh[kk] = v2;
      if (layer > 0) {
        s16x8 v1;
#pragma unroll
        for (int j = 0; j < 8; ++j) v1[j] = (short)f2bf(ihr[k0 + j]);
        bfih[kk] = v1;
      }
    }
  }

  const int ub = tid >> 3;            // batch row this thread updates
  const int jp = tid & 7;             // col-pair within WG
  const int kpglob = (j0 >> 1) + jp;  // global u32 pair index

  float bs[4][2];
#pragma unroll
  for (int g = 0; g < 4; ++g)
#pragma unroll
    for (int c = 0; c < 2; ++c) {
      const size_t r = (size_t)layer * 2048 + g * 512 + j0 + 2 * jp + c;
      float vv = bhh[r];
      if (layer > 0) vv += bih[r];    // L0: b_ih folded into XG0
      bs[g][c] = vv;
    }

  // LN params (of layer-1) for this thread's fixed staging columns {2*tid, 2*tid+1}
  float sc0 = 0.f, sc1v = 0.f, bi0 = 0.f, bi1 = 0.f;
  if (layer > 0) {
    sc0  = lnS[(layer - 1) * 512 + 2 * tid];
    sc1v = lnS[(layer - 1) * 512 + 2 * tid + 1];
    bi0  = lnB[(layer - 1) * 512 + 2 * tid];
    bi1  = lnB[(layer - 1) * 512 + 2 * tid + 1];
  }

  if (layer == 0) {
    float* xg0s = (float*)smem;           // [4][32][16]
    float* xps  = (float*)(smem + 8192);  // [32][16]
    for (int i = tid; i < 2048; i += 256) {
      int g = i >> 9, b = (i >> 4) & 31, jl = i & 15;
      xg0s[i] = XG0[b * 2048 + g * 512 + j0 + jl];
    }
    for (int i = tid; i < 512; i += 256) {
      int b = i >> 4, jl = i & 15;
      xps[i] = XP[b * 512 + j0 + jl];
    }
  }

  // zero own slice of h buffer 0 (h0 = 0)
  __hip_atomic_store(&HstL[(ub << 8) + kpglob], 0u, __ATOMIC_RELAXED, __HIP_MEMORY_SCOPE_AGENT);

  // ---- pre-loop barrier (gen 1) ----
  __syncthreads();
  if (tid == 0)
    __hip_atomic_store(flg + wgid, 1u, __ATOMIC_RELEASE, __HIP_MEMORY_SCOPE_AGENT);
  if (tid < 192) {
    for (;;) {
      unsigned v = __hip_atomic_load(flg + tid, __ATOMIC_RELAXED, __HIP_MEMORY_SCOPE_AGENT);
      if (__all((int)(v >= 1u))) break;
      __builtin_amdgcn_s_sleep(2);
    }
  }
  __syncthreads();

  float xinc0 = 0.f, xinc1 = 0.f;
  if (layer == 0) {
    const float* xps = (const float*)(smem + 8192);
    xinc0 = xps[ub * 16 + 2 * jp];
    xinc1 = xps[ub * 16 + 2 * jp + 1];
  }

  const int rA  = lane & 15;
  const int kg2 = lane >> 4;
  const int swz = (rA & 7) << 4;
  const int ab0 = rA * 1024 + kg2 * 16;
  const int ab1 = ab0 + 16384;

  float creg0 = 0.f, creg1 = 0.f;
  const int tbase = -2 * layer;

#pragma unroll 1
  for (int s = 0; s < NS; ++s) {
    const int t = s + tbase;

    // ================= phase A: compute step t =================
    if (0 <= t && t < 2048) {
      // issue h[t-1] loads (LLC) ...
      unsigned long long hreg[16];
      const unsigned long long* hs = (const unsigned long long*)(HstL + ((t & 1) << 13));
#pragma unroll
      for (int it = 0; it < 16; ++it)
        hreg[it] = __hip_atomic_load(hs + it * 256 + tid, __ATOMIC_RELAXED, __HIP_MEMORY_SCOPE_AGENT);

      // ... while ih-MFMA runs from xarea (staged last superstep)
      float xin0, xin1;
      f32x4 ai0 = {0.f,0.f,0.f,0.f}, ai1 = {0.f,0.f,0.f,0.f};
      if (layer > 0) {
        const unsigned xu = *(const unsigned*)(xarea + (((ub * 1024) + kpglob * 4) ^ ((ub & 7) << 4)));
        xin0 = bflo(xu); xin1 = bfhi(xu);
#pragma unroll
        for (int kk = 0; kk < 16; ++kk) {
          const i32x4 x0 = *(const i32x4*)(xarea + ((ab0 + kk * 64) ^ swz));
          const i32x4 x1 = *(const i32x4*)(xarea + ((ab1 + kk * 64) ^ swz));
          ai0 = __builtin_amdgcn_mfma_f32_16x16x32_bf16(__builtin_bit_cast(s16x8, x0), bfih[kk], ai0, 0, 0, 0);
          ai1 = __builtin_amdgcn_mfma_f32_16x16x32_bf16(__builtin_bit_cast(s16x8, x1), bfih[kk], ai1, 0, 0, 0);
        }
      } else { xin0 = xinc0; xin1 = xinc1; }

      // stage h into LDS (swizzled)
#pragma unroll
      for (int it = 0; it < 16; ++it) {
        const int flat = it * 256 + tid;
        const int q = flat >> 7, kp2 = flat & 127;
        *(unsigned long long*)(harea + ((q * 1024 + kp2 * 8) ^ ((q & 7) << 4))) = hreg[it];
      }
      __syncthreads();

      f32x4 acc0, acc1;
      if (layer > 0) {
        f32x4 ah0 = {0.f,0.f,0.f,0.f}, ah1 = {0.f,0.f,0.f,0.f};
#pragma unroll
        for (int kk = 0; kk < 16; ++kk) {
          const i32x4 h0 = *(const i32x4*)(harea + ((ab0 + kk * 64) ^ swz));
          const i32x4 h1 = *(const i32x4*)(harea + ((ab1 + kk * 64) ^ swz));
          ah0 = __builtin_amdgcn_mfma_f32_16x16x32_bf16(__builtin_bit_cast(s16x8, h0), bfhh[kk], ah0, 0, 0, 0);
          ah1 = __builtin_amdgcn_mfma_f32_16x16x32_bf16(__builtin_bit_cast(s16x8, h1), bfhh[kk], ah1, 0, 0, 0);
        }
        acc0 = ai0 + ah0; acc1 = ai1 + ah1;
      } else {
        f32x4 a0a = {0.f,0.f,0.f,0.f}, a1a = {0.f,0.f,0.f,0.f};
        f32x4 a0b = {0.f,0.f,0.f,0.f}, a1b = {0.f,0.f,0.f,0.f};
#pragma unroll
        for (int kk = 0; kk < 8; ++kk) {
          const i32x4 h0a = *(const i32x4*)(harea + ((ab0 + kk * 64) ^ swz));
          const i32x4 h1a = *(const i32x4*)(harea + ((ab1 + kk * 64) ^ swz));
          const i32x4 h0b = *(const i32x4*)(harea + ((ab0 + (kk + 8) * 64) ^ swz));
          const i32x4 h1b = *(const i32x4*)(harea + ((ab1 + (kk + 8) * 64) ^ swz));
          a0a = __builtin_amdgcn_mfma_f32_16x16x32_bf16(__builtin_bit_cast(s16x8, h0a), bfhh[kk], a0a, 0, 0, 0);
          a1a = __builtin_amdgcn_mfma_f32_16x16x32_bf16(__builtin_bit_cast(s16x8, h1a), bfhh[kk], a1a, 0, 0, 0);
          a0b = __builtin_amdgcn_mfma_f32_16x16x32_bf16(__builtin_bit_cast(s16x8, h0b), bfhh[kk + 8], a0b, 0, 0, 0);
          a1b = __builtin_amdgcn_mfma_f32_16x16x32_bf16(__builtin_bit_cast(s16x8, h1b), bfhh[kk + 8], a1b, 0, 0, 0);
        }
        acc0 = a0a + a0b; acc1 = a1a + a1b;
      }
      __syncthreads();   // xarea/harea reads done before gacc aliases xarea
      {
        float* gp = gacc + (wv * 16 + rA) * 36 + kg2 * 4;
        *(f32x4*)gp        = acc0;
        *(f32x4*)(gp + 16) = acc1;
      }
      __syncthreads();

      float pre[4][2];
#pragma unroll
      for (int g = 0; g < 4; ++g)
#pragma unroll
        for (int c = 0; c < 2; ++c) {
          float vv = gacc[(g * 16 + 2 * jp + c) * 36 + ub] + bs[g][c];
          if (layer == 0) vv += ((const float*)smem)[(g * 32 + ub) * 16 + 2 * jp + c];
          pre[g][c] = vv;
        }

      float i0 = sigm(pre[0][0]), ff0 = sigm(pre[1][0]), g0 = tanh_(pre[2][0]), o0 = sigm(pre[3][0]);
      creg0 = ff0 * creg0 + i0 * g0;
      float h0 = o0 * tanh_(creg0);
      float i1 = sigm(pre[0][1]), ff1 = sigm(pre[1][1]), g1 = tanh_(pre[2][1]), o1 = sigm(pre[3][1]);
      creg1 = ff1 * creg1 + i1 * g1;
      float h1 = o1 * tanh_(creg1);
      const float out0 = h0 + xin0, out1 = h1 + xin1;

      if (layer < 5) {
        float sP  = out0 + out1;
        float ssP = out0 * out0 + out1 * out1;
#pragma unroll
        for (int m = 1; m < 8; m <<= 1) { sP += __shfl_xor(sP, m, 64); ssP += __shfl_xor(ssP, m, 64); }
        __hip_atomic_store(&Roll[layer * 32768 + (t & 3) * 8192 + ub * 256 + kpglob],
                           pack2bf(out0, out1), __ATOMIC_RELAXED, __HIP_MEMORY_SCOPE_AGENT);
        if (jp == 0) {
          unsigned long long pp = (unsigned long long)__float_as_uint(sP) |
                                  ((unsigned long long)__float_as_uint(ssP) << 32);
          __hip_atomic_store(&Part[layer * 4096 + (t & 3) * 1024 + w * 32 + ub],
                             pp, __ATOMIC_RELAXED, __HIP_MEMORY_SCOPE_AGENT);
        }
      } else {
        RB[((size_t)ub * 2048 + t) * 256 + kpglob] = pack2bf(out0, out1);
      }
      __hip_atomic_store(&HstL[(((t + 1) & 1) << 13) + (ub << 8) + kpglob], pack2bf(h0, h1),
                         __ATOMIC_RELAXED, __HIP_MEMORY_SCOPE_AGENT);
    }

    // ================= phase B: flag =================
    __syncthreads();   // gacc/LDS reads done; each wave's vmcnt drained at barrier
    if (tid == 0)
      __hip_atomic_store(flg + wgid, (unsigned)(s + 2), __ATOMIC_RELEASE, __HIP_MEMORY_SCOPE_AGENT);
    if (s == NS - 1) break;

    // ===== phase D: prefetch + LN-stage next input row (off critical path) =====
    const int r = s + 1 + tbase;
    if (layer > 0 && 0 <= r && r < 2048) {
      const unsigned* RollC = Roll + (layer - 1) * 32768 + (r & 3) * 8192;
      unsigned xreg[32];
#pragma unroll
      for (int q = 0; q < 32; ++q)
        xreg[q] = __hip_atomic_load(RollC + q * 256 + tid, __ATOMIC_RELAXED, __HIP_MEMORY_SCOPE_AGENT);

      const unsigned long long* PartC = Part + (layer - 1) * 4096 + (r & 3) * 1024;
      {
        const int b = tid & 31, w8 = tid >> 5;
        float s4 = 0.f, ss4 = 0.f;
#pragma unroll
        for (int k = 0; k < 4; ++k) {
          unsigned long long pp = __hip_atomic_load(PartC + (w8 + 8 * k) * 32 + b,
                                                    __ATOMIC_RELAXED, __HIP_MEMORY_SCOPE_AGENT);
          s4  += __uint_as_float((unsigned)pp);
          ss4 += __uint_as_float((unsigned)(pp >> 32));
        }
        float* scr = (float*)harea;            // [8][32][2]
        scr[(w8 * 32 + b) * 2]     = s4;
        scr[(w8 * 32 + b) * 2 + 1] = ss4;
      }
      __syncthreads();
      float* stats = (float*)(harea + 2048);   // [32][2] = {mu, rs}
      if (tid < 32) {
        const float* scr = (const float*)harea;
        float ssum = 0.f, sssum = 0.f;
#pragma unroll
        for (int k = 0; k < 8; ++k) { ssum += scr[(k * 32 + tid) * 2]; sssum += scr[(k * 32 + tid) * 2 + 1]; }
        const float mu = ssum * (1.f / 512.f);
        float var = sssum * (1.f / 512.f) - mu * mu;
        const float rs = rsqrtf(var + 1e-5f);
        stats[tid * 2]     = mu;
        stats[tid * 2 + 1] = rs;
      }
      __syncthreads();
#pragma unroll
      for (int q = 0; q < 32; ++q) {
        const float mu = stats[q * 2], rs = stats[q * 2 + 1];
        const unsigned u = xreg[q];
        const float a  = (bflo(u) - mu) * rs * sc0  + bi0;
        const float b2 = (bfhi(u) - mu) * rs * sc1v + bi1;
        *(unsigned*)(xarea + ((q * 1024 + tid * 4) ^ ((q & 7) << 4))) = pack2bf(a, b2);
      }
    }

    // ================= phase E: poll =================
    {
      const unsigned need = (unsigned)(s + 2);
      if (tid < 192) {
        for (;;) {
          unsigned v = __hip_atomic_load(flg + tid, __ATOMIC_RELAXED, __HIP_MEMORY_SCOPE_AGENT);
          if (__all((int)(v >= need))) break;
          __builtin_amdgcn_s_sleep(2);
        }
      }
      __syncthreads();
    }
  }
}

// ---------------- fused final LayerNorm + output head ----------------
__global__ __launch_bounds__(256) void k_lnout(const unsigned* __restrict__ Rin,
                                               const float* __restrict__ lnS,
                                               const float* __restrict__ lnB,
                                               const float* __restrict__ ow,
                                               const float* __restrict__ ob,
                                               float* __restrict__ y) {
  int row  = blockIdx.x * 4 + (threadIdx.x >> 6);   // b*T + t
  int lane = threadIdx.x & 63;
  const i32x4 v = *(const i32x4*)(Rin + (size_t)row * 256 + lane * 4);
  float xv[8];
#pragma unroll
  for (int j = 0; j < 4; ++j) {
    unsigned u = (unsigned)v[j];
    xv[2*j]   = bflo(u);
    xv[2*j+1] = bfhi(u);
  }
  float s = 0.f, s2 = 0.f;
#pragma unroll
  for (int j = 0; j < 8; ++j) { s += xv[j]; s2 += xv[j] * xv[j]; }
#pragma unroll
  for (int m = 1; m < 64; m <<= 1) { s += __shfl_xor(s, m, 64); s2 += __shfl_xor(s2, m, 64); }
  float mu  = s * (1.f / 512.f);
  float var = s2 * (1.f / 512.f) - mu * mu;
  float rs  = rsqrtf(var + 1e-5f);
  const float* Sp = lnS + 5 * 512 + lane * 8;
  const float* Bp = lnB + 5 * 512 + lane * 8;
  const float* wp = ow + lane * 8;
  float acc = 0.f;
#pragma unroll
  for (int j = 0; j < 8; ++j)
    acc += ((xv[j] - mu) * rs * Sp[j] + Bp[j]) * wp[j];
#pragma unroll
  for (int m = 1; m < 64; m <<= 1) acc += __shfl_xor(acc, m, 64);
  if (lane == 0) y[row] = acc + ob[0];
}

extern "C" void kernel_launch(void* const* d_in, const int* in_sizes, int n_in,
                              void* d_out, int out_size, void* d_ws, size_t ws_size,
                              hipStream_t stream) {
  (void)in_sizes; (void)n_in; (void)out_size; (void)ws_size;
  const float* x   = (const float*)d_in[0];
  const float* ipw = (const float*)d_in[1];
  const float* ipb = (const float*)d_in[2];
  const float* Wih = (const float*)d_in[3];
  const float* Whh = (const float*)d_in[4];
  const float* bih = (const float*)d_in[5];
  const float* bhh = (const float*)d_in[6];
  const float* lnS = (const float*)d_in[7];
  const float* lnB = (const float*)d_in[8];
  const float* ow  = (const float*)d_in[9];
  const float* ob  = (const float*)d_in[10];
  float* y = (float*)d_out;

  char* ws = (char*)d_ws;
  unsigned* flg            = (unsigned*)ws;                  // 192 u32 (1 KB)
  float* XP                = (float*)(ws + 4096);            // 64 KB
  float* XG0               = (float*)(ws + 69632);           // 256 KB
  unsigned* Hst            = (unsigned*)(ws + 331776);       // 384 KB
  unsigned* Roll           = (unsigned*)(ws + 724992);       // 640 KB
  unsigned long long* Part = (unsigned long long*)(ws + 1380352);  // 160 KB
  unsigned* RB             = (unsigned*)(ws + 2097152);      // 67.1 MB

  hipMemsetAsync(flg, 0, 1024, stream);
  k_inproj<<<64, 256, 0, stream>>>(x, ipw, ipb, XP);
  k_xg0<<<256, 256, 0, stream>>>(XP, Wih, bih, XG0);
  k_pipe<<<192, 256, 0, stream>>>(Wih, Whh, bih, bhh, lnS, lnB, XG0, XP,
                                  Hst, Roll, Part, RB, flg);
  k_lnout<<<16384, 256, 0, stream>>>(RB, lnS, lnB, ow, ob, y);
}